// Round 7
// baseline (315.740 us; speedup 1.0000x reference)
//
#include <hip/hip_runtime.h>
#include <hip/hip_bf16.h>

typedef unsigned short u16;
typedef __attribute__((ext_vector_type(8))) short bfrag;   // 8 x bf16 (4 VGPRs)
typedef __attribute__((ext_vector_type(4))) float ffrag;   // 4 x f32

// ---- problem constants ----
#define NWIN_TOT 1024      // B_ = 16 * 64 windows
#define NTOK 64            // tokens per window
#define CDIM 512
#define NHEAD 16
#define HDIM 32
#define NW 64              // mask windows

__device__ __forceinline__ u16 f2bf(float f) {
  union { float f; unsigned u; } v; v.f = f;
  unsigned r = v.u + 0x7fffu + ((v.u >> 16) & 1u);
  return (u16)(r >> 16);
}

__device__ __forceinline__ float bfhi2f(unsigned hi_bits) {  // bf16 in high 16 bits
  union { unsigned u; float f; } v; v.u = hi_bits; return v.f;
}

__device__ __forceinline__ ffrag mfma16(bfrag a, bfrag b, ffrag c) {
  return __builtin_amdgcn_mfma_f32_16x16x32_bf16(a, b, c, 0, 0, 0);
}

// async global->LDS, 16B per lane, linear LDS dest (wave base + lane*16)
__device__ __forceinline__ void gload16(const u16* src, u16* lds) {
  __builtin_amdgcn_global_load_lds(
      (const __attribute__((address_space(1))) unsigned int*)src,
      (__attribute__((address_space(3))) unsigned int*)lds, 16, 0, 0);
}

#define BAR() __builtin_amdgcn_s_barrier()
#define SCHED0() __builtin_amdgcn_sched_barrier(0)
#define VMW(n) do { asm volatile("s_waitcnt vmcnt(" #n ")" ::: "memory"); \
                    __builtin_amdgcn_sched_barrier(0); } while (0)

// ---------------------------------------------------------------------------
// prep: x -> bf16; weights -> bf16; combined bias+mask table (bf16, row-major)
// ---------------------------------------------------------------------------
__global__ __launch_bounds__(256) void k_prep(const float* __restrict__ x,
                                              const float* __restrict__ qkv_w,
                                              const float* __restrict__ proj_w,
                                              const int*   __restrict__ rel_index,
                                              const float* __restrict__ rpb,
                                              const float* __restrict__ mask,
                                              u16* __restrict__ xb,
                                              u16* __restrict__ wq, u16* __restrict__ wp,
                                              u16* __restrict__ combB) {
  int i = blockIdx.x * 256 + threadIdx.x;
  if (i < 4194304) {            // x -> bf16, 8 elems/thread
    int e = i * 8;
    const float4* xp = reinterpret_cast<const float4*>(x + e);
    float4 lo = xp[0], hi = xp[1];
    union { u16 u[8]; bfrag v; } pk;
    pk.u[0] = f2bf(lo.x); pk.u[1] = f2bf(lo.y); pk.u[2] = f2bf(lo.z); pk.u[3] = f2bf(lo.w);
    pk.u[4] = f2bf(hi.x); pk.u[5] = f2bf(hi.y); pk.u[6] = f2bf(hi.z); pk.u[7] = f2bf(hi.w);
    *reinterpret_cast<bfrag*>(xb + e) = pk.v;
    return;
  }
  i -= 4194304;
  if (i < 786432) { wq[i] = f2bf(qkv_w[i]); return; }
  i -= 786432;
  if (i < 262144) { wp[i] = f2bf(proj_w[i]); return; }
  i -= 262144;
  {                              // combB
    int wh = i >> 12, rc = i & 4095;
    int w0 = wh >> 4, h = wh & 15;
    combB[i] = f2bf(rpb[rel_index[rc] * 16 + h] + mask[(w0 << 12) + rc]);
  }
}

// ---------------------------------------------------------------------------
// 8-phase 256x256 GEMM, BK=64, 8 waves (2M x 4N), K=512 (8 K-tiles).
// K-loop identical to R6 (verified). Epilogue (EPI=0) restages through LDS:
//   which = bn>>1 (block-uniform q/k/v); acc -> LDS[256][256] bf16 with
//   chunk-swizzle (chunk ^= row&31, 16B chunks); __syncthreads; coalesced
//   16B global stores (q/k: b128 row reads; v: 8x u16 column gather).
// ---------------------------------------------------------------------------
#define MFMAQ(mh, nh, BARR) \
  _Pragma("unroll") for (int i_ = 0; i_ < 4; ++i_) \
  _Pragma("unroll") for (int n_ = 0; n_ < 2; ++n_) \
  _Pragma("unroll") for (int ks_ = 0; ks_ < 2; ++ks_) \
    acc[(mh)*4+i_][(nh)*2+n_] = mfma16(a_[i_*2+ks_], BARR[n_*2+ks_], acc[(mh)*4+i_][(nh)*2+n_]);

template<int EPI>
__global__ __launch_bounds__(512, 2) void k_gemm8(const u16* __restrict__ A,
                                                  const u16* __restrict__ W,
                                                  const float* __restrict__ bias,
                                                  u16* __restrict__ qws, u16* __restrict__ kws,
                                                  u16* __restrict__ vws,
                                                  float* __restrict__ out) {
  constexpr int NT = (EPI == 0) ? 6 : 2;           // N / 256
  constexpr int NWG = 256 * NT;                    // grid size (M/256 * NT)
  extern __shared__ __align__(16) u16 smem[];      // [2][2][256][64] = 128 KiB

  // XCD-bijective swizzle (NWG % 8 == 0), N-inner tile order
  const int bid = blockIdx.x;
  const int tile = (bid & 7) * (NWG >> 3) + (bid >> 3);
  const int bn = tile % NT, bm = tile / NT;
  const int brow = bm << 8, bcol = bn << 8;

  const int tid = threadIdx.x;
  const int wv = tid >> 6, lane = tid & 63, c15 = lane & 15, g = lane >> 4;
  const int wr = wv >> 2, wc = wv & 3;             // 2 x 4 wave grid
  const int rowA0 = wr * 128 + c15;                // + mh*64 + i*16
  const int rowB0 = wc * 64 + c15;                 // + nh*32 + n*16
  const ffrag zf = {0.f, 0.f, 0.f, 0.f};

  ffrag acc[8][4];
#pragma unroll
  for (int i = 0; i < 8; ++i)
#pragma unroll
    for (int n = 0; n < 4; ++n) acc[i][n] = zf;

  // stage one half-tile (128 rows x 64 cols) of matrix mat for K-tile t
  auto stage = [&](int t, int mat, int half) {
    u16* db = smem + ((t & 1) * 2 + mat) * 16384 + half * 8192;
    const u16* gsrc = mat ? W : A;
    const int gr0 = (mat ? bcol : brow) + half * 128;
#pragma unroll
    for (int l = 0; l < 2; ++l) {
      int e = l * 4096 + tid * 8;                  // elem in half-tile
      int r = e >> 6, cb = (e & 63) << 1;          // row, byte-col (16-aligned)
      int scol = (cb ^ ((r & 7) << 4)) >> 1;       // inverse-swizzled source col
      gload16(gsrc + (size_t)(gr0 + r) * 512 + t * 64 + scol, db + e);
    }
  };

  // prologue: tiles 0 and 1 (16 loads); vmcnt(8)+BAR => tile0 resident chip-wide
  stage(0, 0, 0); stage(0, 0, 1); stage(0, 1, 0); stage(0, 1, 1);
  stage(1, 0, 0); stage(1, 0, 1); stage(1, 1, 0); stage(1, 1, 1);
  VMW(8);
  BAR();

  bfrag b0_[4];                                    // loop-carried (B nh0 of tile t)
  {
    const char* B0_ = (const char*)(smem + 1 * 16384);
#pragma unroll
    for (int n = 0; n < 2; ++n) {
      int rb = rowB0 + n * 16;
#pragma unroll
      for (int ks = 0; ks < 2; ++ks)
        b0_[n * 2 + ks] = *(const bfrag*)(B0_ + rb * 128 + ((ks * 64 + g * 16) ^ ((rb & 7) << 4)));
    }
  }

  for (int t = 0; t < 8; ++t) {
    const char* As_ = (const char*)(smem + ((t & 1) * 2 + 0) * 16384);
    const char* Bs_ = (const char*)(smem + ((t & 1) * 2 + 1) * 16384);
    bfrag a_[8], b1_[4];

    // ---- P1: ds A(mh0) [8]; MFMA Q(0,0) uses b0_ carried from prev P4 ----
#pragma unroll
    for (int i = 0; i < 4; ++i) {
      int ra = rowA0 + i * 16;
#pragma unroll
      for (int ks = 0; ks < 2; ++ks)
        a_[i * 2 + ks] = *(const bfrag*)(As_ + ra * 128 + ((ks * 64 + g * 16) ^ ((ra & 7) << 4)));
    }
    BAR();
    __builtin_amdgcn_s_setprio(1);
    MFMAQ(0, 0, b0_);
    __builtin_amdgcn_s_setprio(0);
    BAR();

    // ---- P2: ds B(nh1) [4] ----
#pragma unroll
    for (int n = 0; n < 2; ++n) {
      int rb = rowB0 + 32 + n * 16;
#pragma unroll
      for (int ks = 0; ks < 2; ++ks)
        b1_[n * 2 + ks] = *(const bfrag*)(Bs_ + rb * 128 + ((ks * 64 + g * 16) ^ ((rb & 7) << 4)));
    }
    BAR();
    __builtin_amdgcn_s_setprio(1);
    MFMAQ(0, 1, b1_);
    __builtin_amdgcn_s_setprio(0);
    BAR();

    // ---- P3: ds A(mh1) [8]; stage t+2 B halves (B regions free after P2 bar) ----
#pragma unroll
    for (int i = 0; i < 4; ++i) {
      int ra = rowA0 + 64 + i * 16;
#pragma unroll
      for (int ks = 0; ks < 2; ++ks)
        a_[i * 2 + ks] = *(const bfrag*)(As_ + ra * 128 + ((ks * 64 + g * 16) ^ ((ra & 7) << 4)));
    }
    SCHED0();                                      // pin: reads issue before stages
    if (t + 2 < 8) { stage(t + 2, 1, 0); stage(t + 2, 1, 1); }
    BAR();
    __builtin_amdgcn_s_setprio(1);
    MFMAQ(1, 1, b1_);
    __builtin_amdgcn_s_setprio(0);
    BAR();

    // ---- P4: stage t+2 A halves; VMW then BAR (cross-wave t+1 drain);
    //          prefetch b0_ of t+1 from buf nxt [4] ----
    if (t + 2 < 8) { stage(t + 2, 0, 0); stage(t + 2, 0, 1); }
    if (t < 6) { VMW(8); } else if (t == 6) { VMW(0); }
    BAR();
    __builtin_amdgcn_s_setprio(1);
    MFMAQ(1, 0, b0_);
    __builtin_amdgcn_s_setprio(0);
    if (t < 7) {
      const char* Bn_ = (const char*)(smem + (((t + 1) & 1) * 2 + 1) * 16384);
#pragma unroll
      for (int n = 0; n < 2; ++n) {
        int rb = rowB0 + n * 16;
#pragma unroll
        for (int ks = 0; ks < 2; ++ks)
          b0_[n * 2 + ks] = *(const bfrag*)(Bn_ + rb * 128 + ((ks * 64 + g * 16) ^ ((rb & 7) << 4)));
      }
    }
    BAR();
  }

  // ---- epilogue ----
  if (EPI == 0) {
    // D frag mapping: col = c15, row = g*4 + r
    const int which = bn >> 1;                     // 0=q 1=k 2=v (block-uniform)
    const int head0 = (bn & 1) * 8;
    const int win0 = brow >> 6;
    const float s = (which == 0) ? 0.17677669529663687f : 1.0f;
    u16* lds16 = smem;  // [256][256] bf16, chunk-swizzled: chunk ^= row&31

    // 1) acc -> LDS (bias + scale fused)
#pragma unroll
    for (int n = 0; n < 4; ++n) {
      int colc = wc * 64 + n * 16 + c15;           // local col 0..255
      float bz = bias[bcol + colc];
#pragma unroll
      for (int i = 0; i < 8; ++i) {
#pragma unroll
        for (int r = 0; r < 4; ++r) {
          int row = wr * 128 + i * 16 + g * 4 + r;
          int ch = ((colc >> 3) ^ (row & 31)) & 31;
          lds16[row * 256 + (colc & 7) + (ch << 3)] = f2bf((acc[i][n][r] + bz) * s);
        }
      }
    }
    __syncthreads();

    // 2) coalesced 16B stores; G = global chunk id (lane-consecutive)
    if (which < 2) {
      u16* dst = (which == 0) ? qws : kws;         // [win][head][tok][d]
#pragma unroll
      for (int it = 0; it < 16; ++it) {
        int G = it * 512 + tid;
        int win = G >> 11, rem = G & 2047;
        int hl = rem >> 8, rem2 = rem & 255;
        int tok = rem2 >> 2, d0 = (rem2 & 3) << 3;
        int row = win * 64 + tok, col = hl * 32 + d0;
        int ch = ((col >> 3) ^ (row & 31)) & 31;
        bfrag v = *(const bfrag*)(lds16 + row * 256 + (ch << 3));
        size_t o = ((size_t)((win0 + win) * NHEAD + head0 + hl) * NTOK + tok) * HDIM + d0;
        *(bfrag*)(dst + o) = v;
      }
    } else {                                       // v: [win][head][d][tok]
#pragma unroll
      for (int it = 0; it < 16; ++it) {
        int G = it * 512 + tid;
        int win = G >> 11, rem = G & 2047;
        int hl = rem >> 8, rem2 = rem & 255;
        int d = rem2 >> 3, tok0 = (rem2 & 7) << 3;
        int col = hl * 32 + d;
        union { u16 u[8]; bfrag v; } pk;
#pragma unroll
        for (int j = 0; j < 8; ++j) {
          int row = win * 64 + tok0 + j;
          int ch = ((col >> 3) ^ (row & 31)) & 31;
          pk.u[j] = lds16[row * 256 + (col & 7) + (ch << 3)];
        }
        size_t o = ((size_t)((win0 + win) * NHEAD + head0 + hl) * HDIM + d) * NTOK + tok0;
        *(bfrag*)(vws + o) = pk.v;
      }
    }
  } else {
#pragma unroll
    for (int n = 0; n < 4; ++n) {
      int c = bcol + wc * 64 + n * 16 + c15;
      float bz = bias[c];
      float* po = out + (size_t)(brow + wr * 128) * CDIM + c;
#pragma unroll
      for (int i = 0; i < 8; ++i)
#pragma unroll
        for (int r = 0; r < 4; ++r)
          po[(size_t)(i * 16 + g * 4 + r) * CDIM] = acc[i][n][r] + bz;
    }
  }
}

// ---------------------------------------------------------------------------
// attention: 1 wave per (window, head). S^T = mfma(K,Q); softmax in-lane+2shfl;
// bias+mask from combined bf16 table; P -> swizzled LDS -> A-frags; PV via vT;
// y restaged through LDS ([64][136] padded) for coalesced 256B-row stores.
// ---------------------------------------------------------------------------
__global__ __launch_bounds__(256) void k_attn(const u16* __restrict__ qws,
                                              const u16* __restrict__ kws,
                                              const u16* __restrict__ vws,
                                              const u16* __restrict__ combB,
                                              u16* __restrict__ yws) {
  __shared__ __align__(16) u16 plds[4][NTOK * NTOK];  // 8 KiB per wave; reused for y
  const int tid = threadIdx.x, w = tid >> 6, lane = tid & 63;
  const int c15 = lane & 15, g = lane >> 4, g4 = g * 4;
  const int p = blockIdx.x * 4 + w;
  const int b = p >> 4, h = p & 15;

  const u16* qb_ = qws + (size_t)p * (NTOK * HDIM);
  const u16* kb_ = kws + (size_t)p * (NTOK * HDIM);
  bfrag qa[4], ka[4];
#pragma unroll
  for (int t = 0; t < 4; ++t) {
    qa[t] = *reinterpret_cast<const bfrag*>(qb_ + (t * 16 + c15) * HDIM + g * 8);
    ka[t] = *reinterpret_cast<const bfrag*>(kb_ + (t * 16 + c15) * HDIM + g * 8);
  }

  const u16* cB = combB + ((size_t)(((b & (NW - 1)) << 4) + h) << 12);  // [row][col]
  u16* pl = plds[w];
  const ffrag zf = {0.f, 0.f, 0.f, 0.f};

#pragma unroll
  for (int it = 0; it < 4; ++it) {
    int row = it * 16 + c15;           // score row
    float l[4][4];
    float mx = -3.0e38f;
#pragma unroll
    for (int jt = 0; jt < 4; ++jt) {
      ffrag s = mfma16(ka[jt], qa[it], zf);   // S^T tile: D[4g+r][c15]
      uint2 cw = *reinterpret_cast<const uint2*>(cB + row * 64 + jt * 16 + g4);
      l[jt][0] = s[0] + bfhi2f(cw.x << 16);
      l[jt][1] = s[1] + bfhi2f(cw.x & 0xffff0000u);
      l[jt][2] = s[2] + bfhi2f(cw.y << 16);
      l[jt][3] = s[3] + bfhi2f(cw.y & 0xffff0000u);
      mx = fmaxf(mx, fmaxf(fmaxf(l[jt][0], l[jt][1]), fmaxf(l[jt][2], l[jt][3])));
    }
    mx = fmaxf(mx, __shfl_xor(mx, 16));
    mx = fmaxf(mx, __shfl_xor(mx, 32));
    float sum = 0.f;
#pragma unroll
    for (int jt = 0; jt < 4; ++jt)
#pragma unroll
      for (int r = 0; r < 4; ++r) {
        float e = __expf(l[jt][r] - mx);
        l[jt][r] = e;
        sum += e;
      }
    sum += __shfl_xor(sum, 16);
    sum += __shfl_xor(sum, 32);
    float inv = 1.0f / sum;
#pragma unroll
    for (int jt = 0; jt < 4; ++jt) {
      union { u16 u[4]; uint2 v; } pk;
#pragma unroll
      for (int r = 0; r < 4; ++r) pk.u[r] = f2bf(l[jt][r] * inv);
      int off = row * 64 + ((jt * 16 + g4) ^ ((row & 7) << 3));
      *reinterpret_cast<uint2*>(&pl[off]) = pk.v;
    }
  }
  __syncthreads();

  const u16* vb_ = vws + (size_t)p * (HDIM * NTOK);
  ffrag o0[4] = {zf, zf, zf, zf}, o1[4] = {zf, zf, zf, zf};
#pragma unroll
  for (int ks = 0; ks < 2; ++ks) {
    bfrag vf0 = *reinterpret_cast<const bfrag*>(vb_ + c15 * NTOK + ks * 32 + g * 8);
    bfrag vf1 = *reinterpret_cast<const bfrag*>(vb_ + (16 + c15) * NTOK + ks * 32 + g * 8);
#pragma unroll
    for (int i = 0; i < 4; ++i) {
      int prow = i * 16 + c15;
      bfrag pa = *reinterpret_cast<const bfrag*>(
          &pl[prow * 64 + ((ks * 32 + g * 8) ^ ((prow & 7) << 3))]);
      o0[i] = mfma16(pa, vf0, o0[i]);
      o1[i] = mfma16(pa, vf1, o1[i]);
    }
  }
  __syncthreads();                                 // all waves done reading P

  // y -> LDS [64][136] (padded), then block-cooperative coalesced store
  u16* yl = &plds[0][0];
#pragma unroll
  for (int i = 0; i < 4; ++i)
#pragma unroll
    for (int r = 0; r < 4; ++r) {
      int tok = i * 16 + g4 + r;
      yl[tok * 136 + w * 32 + c15] = f2bf(o0[i][r]);
      yl[tok * 136 + w * 32 + 16 + c15] = f2bf(o1[i][r]);
    }
  __syncthreads();
  {
    const int b2 = blockIdx.x >> 2;
    const int h0 = (blockIdx.x * 4) & 15;          // first head of block
    int row = tid >> 2, seg = tid & 3;             // 64 rows x 4 segs of 32 elems
    const u16* src = yl + row * 136 + seg * 32;
    u16* dst = yws + ((size_t)b2 * NTOK + row) * CDIM + h0 * HDIM + seg * 32;
    bfrag v0 = *(const bfrag*)(src);
    bfrag v1 = *(const bfrag*)(src + 8);
    bfrag v2 = *(const bfrag*)(src + 16);
    bfrag v3 = *(const bfrag*)(src + 24);
    *(bfrag*)(dst) = v0;
    *(bfrag*)(dst + 8) = v1;
    *(bfrag*)(dst + 16) = v2;
    *(bfrag*)(dst + 24) = v3;
  }
}

// ---------------------------------------------------------------------------
extern "C" void kernel_launch(void* const* d_in, const int* in_sizes, int n_in,
                              void* d_out, int out_size, void* d_ws, size_t ws_size,
                              hipStream_t stream) {
  const float* x      = (const float*)d_in[0];
  const float* mask   = (const float*)d_in[1];
  const float* qkv_w  = (const float*)d_in[2];
  const float* qkv_b  = (const float*)d_in[3];
  const float* proj_w = (const float*)d_in[4];
  const float* proj_b = (const float*)d_in[5];
  const float* rpb    = (const float*)d_in[6];
  const int*   rel    = (const int*)d_in[7];
  float* out = (float*)d_out;

  char* ws = (char*)d_ws;
  constexpr size_t SZ_QKV = (size_t)NWIN_TOT * NHEAD * NTOK * HDIM * 2;  // 64 MiB each
  u16* qws = (u16*)(ws);
  u16* kws = (u16*)(ws + SZ_QKV);
  u16* vws = (u16*)(ws + 2 * SZ_QKV);
  u16* xb  = (u16*)(ws + 3 * SZ_QKV);   // x as bf16; dead after k_gemm8<0> ...
  u16* yws = xb;                        // ... so yws aliases it (written in k_attn)
  u16* wq  = (u16*)(ws + 4 * SZ_QKV);
  u16* wp  = (u16*)(ws + 4 * SZ_QKV + 1572864);
  u16* combB = (u16*)(ws + 4 * SZ_QKV + 1572864 + 524288);  // 8 MiB

  hipFuncSetAttribute((const void*)k_gemm8<0>,
                      hipFuncAttributeMaxDynamicSharedMemorySize, 131072);
  hipFuncSetAttribute((const void*)k_gemm8<1>,
                      hipFuncAttributeMaxDynamicSharedMemorySize, 131072);

  k_prep<<<dim3(36864), dim3(256), 0, stream>>>(x, qkv_w, proj_w, rel, rpb, mask,
                                                xb, wq, wp, combB);
  k_gemm8<0><<<dim3(256 * 6), dim3(512), 131072, stream>>>(xb, wq, qkv_b, qws, kws, vws, nullptr);
  k_attn<<<dim3(NWIN_TOT * NHEAD / 4), dim3(256), 0, stream>>>(qws, kws, vws, combB, yws);
  k_gemm8<1><<<dim3(256 * 2), dim3(512), 131072, stream>>>(yws, wp, proj_b, nullptr, nullptr, nullptr, out);
}